// Round 1
// baseline (3298.660 us; speedup 1.0000x reference)
//
#include <hip/hip_runtime.h>
#include <hip/hip_bf16.h>

#define Nn 100000
#define Ee 1600000
#define Kk 80000
#define NB ((Nn + 255) / 256)
#define BIGNEG -1e9f

typedef unsigned int uint;

struct Scal {
    uint prefix, remaining, needEq;
    float c1[4];
    float c2;
    uint gmaxOrd;
    float deng;
    float attnum[128];
    uint mxOrd[128];
};

__device__ __forceinline__ uint f2ord(float f) {
    uint b = __float_as_uint(f);
    return (b & 0x80000000u) ? ~b : (b | 0x80000000u);
}
__device__ __forceinline__ float ord2f(uint u) {
    uint b = (u & 0x80000000u) ? (u ^ 0x80000000u) : ~u;
    return __uint_as_float(b);
}
__device__ __forceinline__ float lrelu(float v) { return v > 0.f ? v : 0.2f * v; }

// ---------------- init ----------------
__global__ __launch_bounds__(256) void initK(float* h1, uint* m1, float* den1, float* aggb,
                                             float* out2, uint* m2, float* den2, uint* hist,
                                             Scal* sc) {
    int i = blockIdx.x * 256 + threadIdx.x;
    if (i < Nn * 16) { h1[i] = 0.f; aggb[i] = 0.f; }
    if (i < Nn * 4) { m1[i] = f2ord(BIGNEG); den1[i] = 0.f; }
    if (i < Nn * 128) out2[i] = 0.f;
    if (i < Nn) { m2[i] = f2ord(BIGNEG); den2[i] = 0.f; }
    if (i < 256) hist[i] = 0u;
    if (i < 128) { sc->attnum[i] = 0.f; sc->mxOrd[i] = f2ord(0.0f); }
    if (i == 0) {
        sc->prefix = 0u; sc->remaining = Kk; sc->needEq = 0u;
        sc->deng = 0.f; sc->gmaxOrd = f2ord(-1e30f);
    }
}

__global__ void constK(const float* We1, const float* ae1, const float* We2, const float* ae2,
                       Scal* sc) {
    if (threadIdx.x == 0) {
        for (int h = 0; h < 4; h++) {
            float s = 0.f;
            for (int d = 0; d < 4; d++) s += We1[h * 4 + d] * ae1[h * 4 + d];
            sc->c1[h] = s;
        }
        float s2 = 0.f;
        for (int d = 0; d < 128; d++) s2 += We2[d] * ae2[d];
        sc->c2 = s2;
    }
}

// ---------------- layer 1: node GEMM + attn coefficients ----------------
__global__ __launch_bounds__(256) void nodeL1(const float* __restrict__ x,
                                              const float* __restrict__ W1,
                                              const float* __restrict__ as1,
                                              const float* __restrict__ ad1,
                                              float* __restrict__ hpre,
                                              float* __restrict__ alS1,
                                              float* __restrict__ alD1) {
    __shared__ float Ws[128 * 16];
    __shared__ float s_as[16], s_ad[16];
    for (int i = threadIdx.x; i < 2048; i += 256) Ws[i] = W1[i];
    if (threadIdx.x < 16) { s_as[threadIdx.x] = as1[threadIdx.x]; s_ad[threadIdx.x] = ad1[threadIdx.x]; }
    __syncthreads();
    int n = blockIdx.x * 256 + threadIdx.x;
    if (n >= Nn) return;
    float acc[16];
#pragma unroll
    for (int j = 0; j < 16; j++) acc[j] = 0.f;
    const float4* xr = (const float4*)(x + (size_t)n * 128);
    for (int t4 = 0; t4 < 32; t4++) {
        float4 xv = xr[t4];
#pragma unroll
        for (int j = 0; j < 16; j++) {
            acc[j] += xv.x * Ws[(t4 * 4 + 0) * 16 + j];
            acc[j] += xv.y * Ws[(t4 * 4 + 1) * 16 + j];
            acc[j] += xv.z * Ws[(t4 * 4 + 2) * 16 + j];
            acc[j] += xv.w * Ws[(t4 * 4 + 3) * 16 + j];
        }
    }
    float* hp = hpre + (size_t)n * 16;
#pragma unroll
    for (int j = 0; j < 16; j++) hp[j] = acc[j];
#pragma unroll
    for (int h = 0; h < 4; h++) {
        float s = 0.f, d = 0.f;
#pragma unroll
        for (int q = 0; q < 4; q++) {
            s += acc[h * 4 + q] * s_as[h * 4 + q];
            d += acc[h * 4 + q] * s_ad[h * 4 + q];
        }
        alS1[n * 4 + h] = s;
        alD1[n * 4 + h] = d;
    }
}

__device__ __forceinline__ float edgeLogit1(const int* ei, const float* ea, const float* alS1,
                                            const float* alD1, const Scal* sc, int e, int h,
                                            int* so, int* do_) {
    int s = ei[e], d = ei[Ee + e];
    *so = s; *do_ = d;
    float v = alS1[s * 4 + h] + alD1[d * 4 + h] + ea[e] * sc->c1[h];
    return lrelu(v);
}

__global__ __launch_bounds__(256) void edgeMax1(const int* __restrict__ ei, const float* __restrict__ ea,
                                                const float* __restrict__ alS1, const float* __restrict__ alD1,
                                                const Scal* __restrict__ sc, uint* __restrict__ m1) {
    int tid = blockIdx.x * 256 + threadIdx.x;
    if (tid >= Ee * 4) return;
    int e = tid >> 2, h = tid & 3, s, d;
    float lg = edgeLogit1(ei, ea, alS1, alD1, sc, e, h, &s, &d);
    atomicMax(&m1[d * 4 + h], f2ord(lg));
}

__global__ __launch_bounds__(256) void edgeSum1(const int* __restrict__ ei, const float* __restrict__ ea,
                                                const float* __restrict__ alS1, const float* __restrict__ alD1,
                                                const Scal* __restrict__ sc, const uint* __restrict__ m1,
                                                float* __restrict__ den1) {
    int tid = blockIdx.x * 256 + threadIdx.x;
    if (tid >= Ee * 4) return;
    int e = tid >> 2, h = tid & 3, s, d;
    float lg = edgeLogit1(ei, ea, alS1, alD1, sc, e, h, &s, &d);
    float num = expf(lg - ord2f(m1[d * 4 + h]));
    atomicAdd(&den1[d * 4 + h], num);
}

__global__ __launch_bounds__(256) void edgeScat1(const int* __restrict__ ei, const float* __restrict__ ea,
                                                 const float* __restrict__ alS1, const float* __restrict__ alD1,
                                                 const Scal* __restrict__ sc, const uint* __restrict__ m1,
                                                 const float* __restrict__ den1,
                                                 const float* __restrict__ hpre, float* __restrict__ h1) {
    long tid = (long)blockIdx.x * 256 + threadIdx.x;
    if (tid >= (long)Ee * 16) return;
    int e = (int)(tid >> 4), c = (int)(tid & 15), h = c >> 2, s, d;
    float lg = edgeLogit1(ei, ea, alS1, alD1, sc, e, h, &s, &d);
    float num = expf(lg - ord2f(m1[d * 4 + h]));
    float coef = num / fmaxf(den1[d * 4 + h], 1e-16f);
    atomicAdd(&h1[(size_t)d * 16 + c], coef * hpre[(size_t)s * 16 + c]);
}

__global__ __launch_bounds__(256) void bias1(float* h1, const float* b1) {
    int i = blockIdx.x * 256 + threadIdx.x;
    if (i >= Nn * 16) return;
    float v = h1[i] + b1[i & 15];
    h1[i] = fmaxf(v, 0.f);
}

__global__ __launch_bounds__(256) void aggK(const int* __restrict__ ei, const float* __restrict__ h1,
                                            float* __restrict__ aggb) {
    long tid = (long)blockIdx.x * 256 + threadIdx.x;
    if (tid >= (long)Ee * 16) return;
    int e = (int)(tid >> 4), c = (int)(tid & 15);
    int s = ei[e], d = ei[Ee + e];
    atomicAdd(&aggb[(size_t)d * 16 + c], h1[(size_t)s * 16 + c]);
}

__global__ __launch_bounds__(256) void scoreK(const float* __restrict__ aggb, const float* __restrict__ h1,
                                              const float* __restrict__ Wrel, const float* __restrict__ brel,
                                              const float* __restrict__ Wroot,
                                              float* __restrict__ score, uint* __restrict__ dkey) {
    int n = blockIdx.x * 256 + threadIdx.x;
    if (n >= Nn) return;
    float s = brel[0];
#pragma unroll
    for (int c = 0; c < 16; c++)
        s += aggb[(size_t)n * 16 + c] * Wrel[c] + h1[(size_t)n * 16 + c] * Wroot[c];
    score[n] = s;
    dkey[n] = ~f2ord(s);  // ascending dkey == descending score
}

// ---------------- radix select (k-th smallest dkey) ----------------
__global__ __launch_bounds__(256) void histK(const uint* __restrict__ dkey, const Scal* __restrict__ sc,
                                             uint* __restrict__ hist, int shift) {
    __shared__ uint lh[256];
    lh[threadIdx.x] = 0u;
    __syncthreads();
    int i = blockIdx.x * 256 + threadIdx.x;
    if (i < Nn) {
        uint d = dkey[i];
        bool ok = (shift == 24) || ((d >> (shift + 8)) == sc->prefix);
        if (ok) atomicAdd(&lh[(d >> shift) & 255u], 1u);
    }
    __syncthreads();
    if (lh[threadIdx.x]) atomicAdd(&hist[threadIdx.x], lh[threadIdx.x]);
}

__global__ void selK(Scal* sc, uint* hist) {
    if (threadIdx.x == 0) {
        uint rem = sc->remaining, cum = 0; int sel = 0;
        for (int b = 0; b < 256; b++) {
            uint c = hist[b];
            if (cum + c >= rem) { sel = b; break; }
            cum += c;
        }
        sc->remaining = rem - cum;
        sc->prefix = (sc->prefix << 8) | (uint)sel;
        for (int b = 0; b < 256; b++) hist[b] = 0u;
    }
}

__global__ __launch_bounds__(256) void cntK(const uint* __restrict__ dkey, const Scal* __restrict__ sc,
                                            uint* __restrict__ blkLt, uint* __restrict__ blkEq) {
    int i = blockIdx.x * 256 + threadIdx.x;
    uint ut = sc->prefix;
    bool lt = (i < Nn) && (dkey[i] < ut);
    bool eq = (i < Nn) && (dkey[i] == ut);
    __shared__ uint sl[4], se[4];
    unsigned long long bl = __ballot(lt), be = __ballot(eq);
    int lane = threadIdx.x & 63, w = threadIdx.x >> 6;
    if (lane == 0) { sl[w] = (uint)__popcll(bl); se[w] = (uint)__popcll(be); }
    __syncthreads();
    if (threadIdx.x == 0) {
        blkLt[blockIdx.x] = sl[0] + sl[1] + sl[2] + sl[3];
        blkEq[blockIdx.x] = se[0] + se[1] + se[2] + se[3];
    }
}

__global__ void prefK(Scal* sc, const uint* blkLt, const uint* blkEq, uint* eqPref) {
    if (threadIdx.x == 0) {
        uint tl = 0, te = 0;
        for (int b = 0; b < NB; b++) {
            eqPref[b] = te;
            tl += blkLt[b];
            te += blkEq[b];
        }
        sc->needEq = Kk - tl;
    }
}

__global__ __launch_bounds__(256) void keptK(const uint* __restrict__ dkey, const Scal* __restrict__ sc,
                                             const uint* __restrict__ eqPref, int* __restrict__ kept) {
    int i = blockIdx.x * 256 + threadIdx.x;
    uint ut = sc->prefix, needEq = sc->needEq;
    bool inr = i < Nn;
    uint d = inr ? dkey[i] : 0xFFFFFFFFu;
    bool isLt = inr && (d < ut);
    bool isEq = inr && (d == ut);
    __shared__ uint wcnt[4];
    unsigned long long mask = __ballot(isEq);
    int lane = threadIdx.x & 63, w = threadIdx.x >> 6;
    uint lanePre = (uint)__popcll(mask & ((1ull << lane) - 1ull));
    if (lane == 0) wcnt[w] = (uint)__popcll(mask);
    __syncthreads();
    uint wo = 0;
    for (int q = 0; q < 4; q++) if (q < w) wo += wcnt[q];
    uint rank = eqPref[blockIdx.x] + wo + lanePre;
    if (inr) kept[i] = (isLt || (isEq && rank < needEq)) ? 1 : 0;
}

// ---------------- layer 2 ----------------
__global__ __launch_bounds__(256) void nodeL2(const float* __restrict__ h1, const float* __restrict__ score,
                                              const int* __restrict__ kept, const float* __restrict__ W2,
                                              const float* __restrict__ as2, const float* __restrict__ ad2,
                                              float* __restrict__ h2pre, float* __restrict__ alS2,
                                              float* __restrict__ alD2) {
    __shared__ float Ws[16 * 128];
    for (int i = threadIdx.x; i < 2048; i += 256) Ws[i] = W2[i];
    __syncthreads();
    int wid = (blockIdx.x * 256 + threadIdx.x) >> 6;
    int lane = threadIdx.x & 63;
    if (wid >= Nn) return;
    int n = wid;
    if (!kept[n]) return;
    float t = tanhf(score[n]);
    float x2[16];
    const float* hr = h1 + (size_t)n * 16;
#pragma unroll
    for (int j = 0; j < 16; j++) x2[j] = hr[j] * t;
    int d0 = lane, d1 = lane + 64;
    float a0 = 0.f, a1 = 0.f;
#pragma unroll
    for (int j = 0; j < 16; j++) {
        a0 += x2[j] * Ws[j * 128 + d0];
        a1 += x2[j] * Ws[j * 128 + d1];
    }
    h2pre[(size_t)n * 128 + d0] = a0;
    h2pre[(size_t)n * 128 + d1] = a1;
    float s = a0 * as2[d0] + a1 * as2[d1];
    float dd = a0 * ad2[d0] + a1 * ad2[d1];
#pragma unroll
    for (int off = 32; off; off >>= 1) { s += __shfl_xor(s, off); dd += __shfl_xor(dd, off); }
    if (lane == 0) { alS2[n] = s; alD2[n] = dd; }
}

__global__ __launch_bounds__(256) void edgeMax2(const int* __restrict__ ei, const float* __restrict__ ea,
                                                const int* __restrict__ kept, const float* __restrict__ alS2,
                                                const float* __restrict__ alD2, const Scal* __restrict__ sc,
                                                uint* __restrict__ m2) {
    int e = blockIdx.x * 256 + threadIdx.x;
    if (e >= Ee) return;
    int s = ei[e], d = ei[Ee + e];
    if (!kept[s] || !kept[d]) return;
    float v = lrelu(alS2[s] + alD2[d] + ea[e] * sc->c2);
    atomicMax(&m2[d], f2ord(v));
}

__global__ __launch_bounds__(256) void edgeSum2(const int* __restrict__ ei, const float* __restrict__ ea,
                                                const int* __restrict__ kept, const float* __restrict__ alS2,
                                                const float* __restrict__ alD2, const Scal* __restrict__ sc,
                                                const uint* __restrict__ m2, float* __restrict__ den2) {
    int e = blockIdx.x * 256 + threadIdx.x;
    if (e >= Ee) return;
    int s = ei[e], d = ei[Ee + e];
    if (!kept[s] || !kept[d]) return;
    float v = lrelu(alS2[s] + alD2[d] + ea[e] * sc->c2);
    float num = expf(v - ord2f(m2[d]));
    atomicAdd(&den2[d], num);
}

__global__ __launch_bounds__(256) void edgeScat2(const int* __restrict__ ei, const float* __restrict__ ea,
                                                 const int* __restrict__ kept, const float* __restrict__ alS2,
                                                 const float* __restrict__ alD2, const Scal* __restrict__ sc,
                                                 const uint* __restrict__ m2, const float* __restrict__ den2,
                                                 const float* __restrict__ h2pre, float* __restrict__ out2) {
    int wid = (blockIdx.x * 256 + threadIdx.x) >> 6;
    int lane = threadIdx.x & 63;
    if (wid >= Ee) return;
    int e = wid;
    int s = ei[e], d = ei[Ee + e];
    if (!kept[s] || !kept[d]) return;
    float v = lrelu(alS2[s] + alD2[d] + ea[e] * sc->c2);
    float num = expf(v - ord2f(m2[d]));
    float coef = num / fmaxf(den2[d], 1e-16f);
    const float* hp = h2pre + (size_t)s * 128;
    float* op = out2 + (size_t)d * 128;
    atomicAdd(&op[lane], coef * hp[lane]);
    atomicAdd(&op[lane + 64], coef * hp[lane + 64]);
}

__global__ __launch_bounds__(256) void h2fin(float* __restrict__ out2, const float* __restrict__ b2,
                                             const float* __restrict__ Wg, const float* __restrict__ bg,
                                             const int* __restrict__ kept, float* __restrict__ gsc,
                                             Scal* sc) {
    int wid = (blockIdx.x * 256 + threadIdx.x) >> 6;
    int lane = threadIdx.x & 63;
    if (wid >= Nn) return;
    int n = wid;
    if (!kept[n]) return;
    float* orow = out2 + (size_t)n * 128;
    float h0 = fmaxf(orow[lane] + b2[lane], 0.f);
    float h1v = fmaxf(orow[lane + 64] + b2[lane + 64], 0.f);
    orow[lane] = h0;
    orow[lane + 64] = h1v;
    float g = h0 * Wg[lane] + h1v * Wg[lane + 64];
#pragma unroll
    for (int off = 32; off; off >>= 1) g += __shfl_xor(g, off);
    if (lane == 0) {
        g += bg[0];
        gsc[n] = g;
        atomicMax(&sc->gmaxOrd, f2ord(g));
    }
    atomicMax(&sc->mxOrd[lane], f2ord(h0));
    atomicMax(&sc->mxOrd[lane + 64], f2ord(h1v));
}

#define CHUNK 256
__global__ __launch_bounds__(128) void gateK(const float* __restrict__ out2, const float* __restrict__ gsc,
                                             const int* __restrict__ kept, Scal* sc) {
    int d = threadIdx.x;
    float gmax = ord2f(sc->gmaxOrd);
    float acc = 0.f, dacc = 0.f;
    int start = blockIdx.x * CHUNK;
    int end = start + CHUNK;
    if (end > Nn) end = Nn;
    for (int n = start; n < end; n++) {
        if (!kept[n]) continue;
        float e = expf(gsc[n] - gmax);
        acc += e * out2[(size_t)n * 128 + d];
        if (d == 0) dacc += e;
    }
    atomicAdd(&sc->attnum[d], acc);
    if (d == 0) atomicAdd(&sc->deng, dacc);
}

__global__ void outK(const Scal* sc, float* out) {
    int d = threadIdx.x;
    if (d < 128) {
        out[d] = sc->attnum[d] / sc->deng;
        out[128 + d] = ord2f(sc->mxOrd[d]);
    }
}

extern "C" void kernel_launch(void* const* d_in, const int* in_sizes, int n_in,
                              void* d_out, int out_size, void* d_ws, size_t ws_size,
                              hipStream_t stream) {
    const float* x = (const float*)d_in[0];
    const int* ei = (const int*)d_in[1];
    const float* ea = (const float*)d_in[2];
    const float* W1 = (const float*)d_in[3];
    const float* as1 = (const float*)d_in[4];
    const float* ad1 = (const float*)d_in[5];
    const float* We1 = (const float*)d_in[6];
    const float* ae1 = (const float*)d_in[7];
    const float* b1 = (const float*)d_in[8];
    const float* Wrel = (const float*)d_in[9];
    const float* brel = (const float*)d_in[10];
    const float* Wroot = (const float*)d_in[11];
    const float* W2 = (const float*)d_in[12];
    const float* as2 = (const float*)d_in[13];
    const float* ad2 = (const float*)d_in[14];
    const float* We2 = (const float*)d_in[15];
    const float* ae2 = (const float*)d_in[16];
    const float* b2 = (const float*)d_in[17];
    const float* Wg = (const float*)d_in[18];
    const float* bg = (const float*)d_in[19];
    float* out = (float*)d_out;

    float* base = (float*)d_ws;
    size_t o = 0;
    auto alloc = [&](size_t nf) { float* p = base + o; o += nf; return p; };
    float* hpre = alloc((size_t)Nn * 16);
    float* h1 = alloc((size_t)Nn * 16);
    float* alS1 = alloc((size_t)Nn * 4);
    float* alD1 = alloc((size_t)Nn * 4);
    uint* m1 = (uint*)alloc((size_t)Nn * 4);
    float* den1 = alloc((size_t)Nn * 4);
    float* aggb = alloc((size_t)Nn * 16);
    float* score = alloc(Nn);
    uint* dkey = (uint*)alloc(Nn);
    int* kept = (int*)alloc(Nn);
    float* h2pre = alloc((size_t)Nn * 128);
    float* out2 = alloc((size_t)Nn * 128);
    float* alS2 = alloc(Nn);
    float* alD2 = alloc(Nn);
    uint* m2 = (uint*)alloc(Nn);
    float* den2 = alloc(Nn);
    float* gsc = alloc(Nn);
    uint* hist = (uint*)alloc(256);
    uint* blkLt = (uint*)alloc(NB);
    uint* blkEq = (uint*)alloc(NB);
    uint* eqPref = (uint*)alloc(NB);
    Scal* sc = (Scal*)alloc(512);

    auto cdiv = [](long a, long b) { return (int)((a + b - 1) / b); };

    initK<<<cdiv((long)Nn * 128, 256), 256, 0, stream>>>(h1, m1, den1, aggb, out2, m2, den2, hist, sc);
    constK<<<1, 64, 0, stream>>>(We1, ae1, We2, ae2, sc);
    nodeL1<<<NB, 256, 0, stream>>>(x, W1, as1, ad1, hpre, alS1, alD1);
    edgeMax1<<<cdiv((long)Ee * 4, 256), 256, 0, stream>>>(ei, ea, alS1, alD1, sc, m1);
    edgeSum1<<<cdiv((long)Ee * 4, 256), 256, 0, stream>>>(ei, ea, alS1, alD1, sc, m1, den1);
    edgeScat1<<<cdiv((long)Ee * 16, 256), 256, 0, stream>>>(ei, ea, alS1, alD1, sc, m1, den1, hpre, h1);
    bias1<<<cdiv((long)Nn * 16, 256), 256, 0, stream>>>(h1, b1);
    aggK<<<cdiv((long)Ee * 16, 256), 256, 0, stream>>>(ei, h1, aggb);
    scoreK<<<NB, 256, 0, stream>>>(aggb, h1, Wrel, brel, Wroot, score, dkey);
    for (int shift = 24; shift >= 0; shift -= 8) {
        histK<<<NB, 256, 0, stream>>>(dkey, sc, hist, shift);
        selK<<<1, 64, 0, stream>>>(sc, hist);
    }
    cntK<<<NB, 256, 0, stream>>>(dkey, sc, blkLt, blkEq);
    prefK<<<1, 64, 0, stream>>>(sc, blkLt, blkEq, eqPref);
    keptK<<<NB, 256, 0, stream>>>(dkey, sc, eqPref, kept);
    nodeL2<<<cdiv(Nn, 4), 256, 0, stream>>>(h1, score, kept, W2, as2, ad2, h2pre, alS2, alD2);
    edgeMax2<<<cdiv(Ee, 256), 256, 0, stream>>>(ei, ea, kept, alS2, alD2, sc, m2);
    edgeSum2<<<cdiv(Ee, 256), 256, 0, stream>>>(ei, ea, kept, alS2, alD2, sc, m2, den2);
    edgeScat2<<<cdiv(Ee, 4), 256, 0, stream>>>(ei, ea, kept, alS2, alD2, sc, m2, den2, h2pre, out2);
    h2fin<<<cdiv(Nn, 4), 256, 0, stream>>>(out2, b2, Wg, bg, kept, gsc, sc);
    gateK<<<cdiv(Nn, CHUNK), 128, 0, stream>>>(out2, gsc, kept, sc);
    outK<<<1, 128, 0, stream>>>(sc, out);
}

// Round 2
// 1233.921 us; speedup vs baseline: 2.6733x; 2.6733x over previous
//
#include <hip/hip_runtime.h>
#include <hip/hip_bf16.h>

#define Nn 100000
#define Ee 1600000
#define Kk 80000
#define NB ((Nn + 255) / 256)
#define BIGNEG -1e9f

typedef unsigned int uint;

struct Scal {
    uint prefix, remaining, needEq;
    float c1[4];
    float c2;
    uint gmaxOrd;
    float deng;
    float attnum[128];
    uint mxOrd[128];
};

__device__ __forceinline__ uint f2ord(float f) {
    uint b = __float_as_uint(f);
    return (b & 0x80000000u) ? ~b : (b | 0x80000000u);
}
__device__ __forceinline__ float ord2f(uint u) {
    uint b = (u & 0x80000000u) ? (u ^ 0x80000000u) : ~u;
    return __uint_as_float(b);
}
__device__ __forceinline__ float lrelu(float v) { return v > 0.f ? v : 0.2f * v; }

// ---------------- init ----------------
__global__ __launch_bounds__(256) void initK(float* h1, uint* m1, float* den1, float* aggb,
                                             float* out2, uint* m2, float* den2, uint* hist,
                                             Scal* sc) {
    int i = blockIdx.x * 256 + threadIdx.x;
    if (i < Nn * 16) { h1[i] = 0.f; aggb[i] = 0.f; }
    if (i < Nn * 4) { m1[i] = f2ord(BIGNEG); den1[i] = 0.f; }
    if (i < Nn * 128) out2[i] = 0.f;
    if (i < Nn) { m2[i] = f2ord(BIGNEG); den2[i] = 0.f; }
    if (i < 256) hist[i] = 0u;
    if (i < 128) { sc->attnum[i] = 0.f; sc->mxOrd[i] = f2ord(0.0f); }
    if (i == 0) {
        sc->prefix = 0u; sc->remaining = Kk; sc->needEq = 0u;
        sc->deng = 0.f; sc->gmaxOrd = f2ord(-1e30f);
    }
}

__global__ void constK(const float* We1, const float* ae1, const float* We2, const float* ae2,
                       Scal* sc) {
    if (threadIdx.x == 0) {
        for (int h = 0; h < 4; h++) {
            float s = 0.f;
            for (int d = 0; d < 4; d++) s += We1[h * 4 + d] * ae1[h * 4 + d];
            sc->c1[h] = s;
        }
        float s2 = 0.f;
        for (int d = 0; d < 128; d++) s2 += We2[d] * ae2[d];
        sc->c2 = s2;
    }
}

// ---------------- layer 1: node GEMM + attn coefficients ----------------
__global__ __launch_bounds__(256) void nodeL1(const float* __restrict__ x,
                                              const float* __restrict__ W1,
                                              const float* __restrict__ as1,
                                              const float* __restrict__ ad1,
                                              float* __restrict__ hpre,
                                              float* __restrict__ alS1,
                                              float* __restrict__ alD1) {
    __shared__ float Ws[128 * 16];
    __shared__ float s_as[16], s_ad[16];
    for (int i = threadIdx.x; i < 2048; i += 256) Ws[i] = W1[i];
    if (threadIdx.x < 16) { s_as[threadIdx.x] = as1[threadIdx.x]; s_ad[threadIdx.x] = ad1[threadIdx.x]; }
    __syncthreads();
    int n = blockIdx.x * 256 + threadIdx.x;
    if (n >= Nn) return;
    float acc[16];
#pragma unroll
    for (int j = 0; j < 16; j++) acc[j] = 0.f;
    const float4* xr = (const float4*)(x + (size_t)n * 128);
    for (int t4 = 0; t4 < 32; t4++) {
        float4 xv = xr[t4];
#pragma unroll
        for (int j = 0; j < 16; j++) {
            acc[j] += xv.x * Ws[(t4 * 4 + 0) * 16 + j];
            acc[j] += xv.y * Ws[(t4 * 4 + 1) * 16 + j];
            acc[j] += xv.z * Ws[(t4 * 4 + 2) * 16 + j];
            acc[j] += xv.w * Ws[(t4 * 4 + 3) * 16 + j];
        }
    }
    float* hp = hpre + (size_t)n * 16;
#pragma unroll
    for (int j = 0; j < 16; j++) hp[j] = acc[j];
#pragma unroll
    for (int h = 0; h < 4; h++) {
        float s = 0.f, d = 0.f;
#pragma unroll
        for (int q = 0; q < 4; q++) {
            s += acc[h * 4 + q] * s_as[h * 4 + q];
            d += acc[h * 4 + q] * s_ad[h * 4 + q];
        }
        alS1[n * 4 + h] = s;
        alD1[n * 4 + h] = d;
    }
}

__device__ __forceinline__ float edgeLogit1(const int* ei, const float* ea, const float* alS1,
                                            const float* alD1, const Scal* sc, int e, int h,
                                            int* so, int* do_) {
    int s = ei[e], d = ei[Ee + e];
    *so = s; *do_ = d;
    float v = alS1[s * 4 + h] + alD1[d * 4 + h] + ea[e] * sc->c1[h];
    return lrelu(v);
}

__global__ __launch_bounds__(256) void edgeMax1(const int* __restrict__ ei, const float* __restrict__ ea,
                                                const float* __restrict__ alS1, const float* __restrict__ alD1,
                                                const Scal* __restrict__ sc, uint* __restrict__ m1) {
    int tid = blockIdx.x * 256 + threadIdx.x;
    if (tid >= Ee * 4) return;
    int e = tid >> 2, h = tid & 3, s, d;
    float lg = edgeLogit1(ei, ea, alS1, alD1, sc, e, h, &s, &d);
    atomicMax(&m1[d * 4 + h], f2ord(lg));
}

__global__ __launch_bounds__(256) void edgeSum1(const int* __restrict__ ei, const float* __restrict__ ea,
                                                const float* __restrict__ alS1, const float* __restrict__ alD1,
                                                const Scal* __restrict__ sc, const uint* __restrict__ m1,
                                                float* __restrict__ den1) {
    int tid = blockIdx.x * 256 + threadIdx.x;
    if (tid >= Ee * 4) return;
    int e = tid >> 2, h = tid & 3, s, d;
    float lg = edgeLogit1(ei, ea, alS1, alD1, sc, e, h, &s, &d);
    float num = expf(lg - ord2f(m1[d * 4 + h]));
    atomicAdd(&den1[d * 4 + h], num);
}

__global__ __launch_bounds__(256) void edgeScat1(const int* __restrict__ ei, const float* __restrict__ ea,
                                                 const float* __restrict__ alS1, const float* __restrict__ alD1,
                                                 const Scal* __restrict__ sc, const uint* __restrict__ m1,
                                                 const float* __restrict__ den1,
                                                 const float* __restrict__ hpre, float* __restrict__ h1) {
    long tid = (long)blockIdx.x * 256 + threadIdx.x;
    if (tid >= (long)Ee * 16) return;
    int e = (int)(tid >> 4), c = (int)(tid & 15), h = c >> 2, s, d;
    float lg = edgeLogit1(ei, ea, alS1, alD1, sc, e, h, &s, &d);
    float num = expf(lg - ord2f(m1[d * 4 + h]));
    float coef = num / fmaxf(den1[d * 4 + h], 1e-16f);
    atomicAdd(&h1[(size_t)d * 16 + c], coef * hpre[(size_t)s * 16 + c]);
}

__global__ __launch_bounds__(256) void bias1(float* h1, const float* b1) {
    int i = blockIdx.x * 256 + threadIdx.x;
    if (i >= Nn * 16) return;
    float v = h1[i] + b1[i & 15];
    h1[i] = fmaxf(v, 0.f);
}

__global__ __launch_bounds__(256) void aggK(const int* __restrict__ ei, const float* __restrict__ h1,
                                            float* __restrict__ aggb) {
    long tid = (long)blockIdx.x * 256 + threadIdx.x;
    if (tid >= (long)Ee * 16) return;
    int e = (int)(tid >> 4), c = (int)(tid & 15);
    int s = ei[e], d = ei[Ee + e];
    atomicAdd(&aggb[(size_t)d * 16 + c], h1[(size_t)s * 16 + c]);
}

__global__ __launch_bounds__(256) void scoreK(const float* __restrict__ aggb, const float* __restrict__ h1,
                                              const float* __restrict__ Wrel, const float* __restrict__ brel,
                                              const float* __restrict__ Wroot,
                                              float* __restrict__ score, uint* __restrict__ dkey) {
    int n = blockIdx.x * 256 + threadIdx.x;
    if (n >= Nn) return;
    float s = brel[0];
#pragma unroll
    for (int c = 0; c < 16; c++)
        s += aggb[(size_t)n * 16 + c] * Wrel[c] + h1[(size_t)n * 16 + c] * Wroot[c];
    score[n] = s;
    dkey[n] = ~f2ord(s);  // ascending dkey == descending score
}

// ---------------- radix select (k-th smallest dkey) ----------------
__global__ __launch_bounds__(256) void histK(const uint* __restrict__ dkey, const Scal* __restrict__ sc,
                                             uint* __restrict__ hist, int shift) {
    __shared__ uint lh[256];
    lh[threadIdx.x] = 0u;
    __syncthreads();
    int i = blockIdx.x * 256 + threadIdx.x;
    if (i < Nn) {
        uint d = dkey[i];
        bool ok = (shift == 24) || ((d >> (shift + 8)) == sc->prefix);
        if (ok) atomicAdd(&lh[(d >> shift) & 255u], 1u);
    }
    __syncthreads();
    if (lh[threadIdx.x]) atomicAdd(&hist[threadIdx.x], lh[threadIdx.x]);
}

__global__ void selK(Scal* sc, uint* hist) {
    if (threadIdx.x == 0) {
        uint rem = sc->remaining, cum = 0; int sel = 0;
        for (int b = 0; b < 256; b++) {
            uint c = hist[b];
            if (cum + c >= rem) { sel = b; break; }
            cum += c;
        }
        sc->remaining = rem - cum;
        sc->prefix = (sc->prefix << 8) | (uint)sel;
        for (int b = 0; b < 256; b++) hist[b] = 0u;
    }
}

__global__ __launch_bounds__(256) void cntK(const uint* __restrict__ dkey, const Scal* __restrict__ sc,
                                            uint* __restrict__ blkLt, uint* __restrict__ blkEq) {
    int i = blockIdx.x * 256 + threadIdx.x;
    uint ut = sc->prefix;
    bool lt = (i < Nn) && (dkey[i] < ut);
    bool eq = (i < Nn) && (dkey[i] == ut);
    __shared__ uint sl[4], se[4];
    unsigned long long bl = __ballot(lt), be = __ballot(eq);
    int lane = threadIdx.x & 63, w = threadIdx.x >> 6;
    if (lane == 0) { sl[w] = (uint)__popcll(bl); se[w] = (uint)__popcll(be); }
    __syncthreads();
    if (threadIdx.x == 0) {
        blkLt[blockIdx.x] = sl[0] + sl[1] + sl[2] + sl[3];
        blkEq[blockIdx.x] = se[0] + se[1] + se[2] + se[3];
    }
}

__global__ void prefK(Scal* sc, const uint* blkLt, const uint* blkEq, uint* eqPref) {
    if (threadIdx.x == 0) {
        uint tl = 0, te = 0;
        for (int b = 0; b < NB; b++) {
            eqPref[b] = te;
            tl += blkLt[b];
            te += blkEq[b];
        }
        sc->needEq = Kk - tl;
    }
}

__global__ __launch_bounds__(256) void keptK(const uint* __restrict__ dkey, const Scal* __restrict__ sc,
                                             const uint* __restrict__ eqPref, int* __restrict__ kept) {
    int i = blockIdx.x * 256 + threadIdx.x;
    uint ut = sc->prefix, needEq = sc->needEq;
    bool inr = i < Nn;
    uint d = inr ? dkey[i] : 0xFFFFFFFFu;
    bool isLt = inr && (d < ut);
    bool isEq = inr && (d == ut);
    __shared__ uint wcnt[4];
    unsigned long long mask = __ballot(isEq);
    int lane = threadIdx.x & 63, w = threadIdx.x >> 6;
    uint lanePre = (uint)__popcll(mask & ((1ull << lane) - 1ull));
    if (lane == 0) wcnt[w] = (uint)__popcll(mask);
    __syncthreads();
    uint wo = 0;
    for (int q = 0; q < 4; q++) if (q < w) wo += wcnt[q];
    uint rank = eqPref[blockIdx.x] + wo + lanePre;
    if (inr) kept[i] = (isLt || (isEq && rank < needEq)) ? 1 : 0;
}

// ---------------- layer 2 ----------------
__global__ __launch_bounds__(256) void nodeL2(const float* __restrict__ h1, const float* __restrict__ score,
                                              const int* __restrict__ kept, const float* __restrict__ W2,
                                              const float* __restrict__ as2, const float* __restrict__ ad2,
                                              float* __restrict__ h2pre, float* __restrict__ alS2,
                                              float* __restrict__ alD2) {
    __shared__ float Ws[16 * 128];
    for (int i = threadIdx.x; i < 2048; i += 256) Ws[i] = W2[i];
    __syncthreads();
    int wid = (blockIdx.x * 256 + threadIdx.x) >> 6;
    int lane = threadIdx.x & 63;
    if (wid >= Nn) return;
    int n = wid;
    if (!kept[n]) return;
    float t = tanhf(score[n]);
    float x2[16];
    const float* hr = h1 + (size_t)n * 16;
#pragma unroll
    for (int j = 0; j < 16; j++) x2[j] = hr[j] * t;
    int d0 = lane, d1 = lane + 64;
    float a0 = 0.f, a1 = 0.f;
#pragma unroll
    for (int j = 0; j < 16; j++) {
        a0 += x2[j] * Ws[j * 128 + d0];
        a1 += x2[j] * Ws[j * 128 + d1];
    }
    h2pre[(size_t)n * 128 + d0] = a0;
    h2pre[(size_t)n * 128 + d1] = a1;
    float s = a0 * as2[d0] + a1 * as2[d1];
    float dd = a0 * ad2[d0] + a1 * ad2[d1];
#pragma unroll
    for (int off = 32; off; off >>= 1) { s += __shfl_xor(s, off); dd += __shfl_xor(dd, off); }
    if (lane == 0) { alS2[n] = s; alD2[n] = dd; }
}

__global__ __launch_bounds__(256) void edgeMax2(const int* __restrict__ ei, const float* __restrict__ ea,
                                                const int* __restrict__ kept, const float* __restrict__ alS2,
                                                const float* __restrict__ alD2, const Scal* __restrict__ sc,
                                                uint* __restrict__ m2) {
    int e = blockIdx.x * 256 + threadIdx.x;
    if (e >= Ee) return;
    int s = ei[e], d = ei[Ee + e];
    if (!kept[s] || !kept[d]) return;
    float v = lrelu(alS2[s] + alD2[d] + ea[e] * sc->c2);
    atomicMax(&m2[d], f2ord(v));
}

__global__ __launch_bounds__(256) void edgeSum2(const int* __restrict__ ei, const float* __restrict__ ea,
                                                const int* __restrict__ kept, const float* __restrict__ alS2,
                                                const float* __restrict__ alD2, const Scal* __restrict__ sc,
                                                const uint* __restrict__ m2, float* __restrict__ den2) {
    int e = blockIdx.x * 256 + threadIdx.x;
    if (e >= Ee) return;
    int s = ei[e], d = ei[Ee + e];
    if (!kept[s] || !kept[d]) return;
    float v = lrelu(alS2[s] + alD2[d] + ea[e] * sc->c2);
    float num = expf(v - ord2f(m2[d]));
    atomicAdd(&den2[d], num);
}

__global__ __launch_bounds__(256) void edgeScat2(const int* __restrict__ ei, const float* __restrict__ ea,
                                                 const int* __restrict__ kept, const float* __restrict__ alS2,
                                                 const float* __restrict__ alD2, const Scal* __restrict__ sc,
                                                 const uint* __restrict__ m2, const float* __restrict__ den2,
                                                 const float* __restrict__ h2pre, float* __restrict__ out2) {
    int wid = (blockIdx.x * 256 + threadIdx.x) >> 6;
    int lane = threadIdx.x & 63;
    if (wid >= Ee) return;
    int e = wid;
    int s = ei[e], d = ei[Ee + e];
    if (!kept[s] || !kept[d]) return;
    float v = lrelu(alS2[s] + alD2[d] + ea[e] * sc->c2);
    float num = expf(v - ord2f(m2[d]));
    float coef = num / fmaxf(den2[d], 1e-16f);
    const float* hp = h2pre + (size_t)s * 128;
    float* op = out2 + (size_t)d * 128;
    atomicAdd(&op[lane], coef * hp[lane]);
    atomicAdd(&op[lane + 64], coef * hp[lane + 64]);
}

// gate score per kept node + block-reduced global max (1 atomic per block)
__global__ __launch_bounds__(256) void h2finA(const float* __restrict__ out2, const float* __restrict__ b2,
                                              const float* __restrict__ Wg, const float* __restrict__ bg,
                                              const int* __restrict__ kept, float* __restrict__ gsc,
                                              Scal* sc) {
    __shared__ float s_b2[128], s_wg[128];
    __shared__ float wmax[4];
    if (threadIdx.x < 128) { s_b2[threadIdx.x] = b2[threadIdx.x]; s_wg[threadIdx.x] = Wg[threadIdx.x]; }
    __syncthreads();
    int w = threadIdx.x >> 6, lane = threadIdx.x & 63;
    float bg0 = bg[0];
    float localmax = -1e30f;
    for (int n = blockIdx.x * 4 + w; n < Nn; n += gridDim.x * 4) {
        if (!kept[n]) continue;
        const float* orow = out2 + (size_t)n * 128;
        float h0 = fmaxf(orow[lane] + s_b2[lane], 0.f);
        float h1v = fmaxf(orow[lane + 64] + s_b2[lane + 64], 0.f);
        float g = h0 * s_wg[lane] + h1v * s_wg[lane + 64];
#pragma unroll
        for (int off = 32; off; off >>= 1) g += __shfl_xor(g, off);
        g += bg0;                      // uniform across the wave after butterfly
        if (lane == 0) gsc[n] = g;
        localmax = fmaxf(localmax, g);
    }
    if (lane == 0) wmax[w] = localmax;
    __syncthreads();
    if (threadIdx.x == 0) {
        float m = fmaxf(fmaxf(wmax[0], wmax[1]), fmaxf(wmax[2], wmax[3]));
        atomicMax(&sc->gmaxOrd, f2ord(m));
    }
}

// gate-weighted sum + per-dim column max, block-chunked: 1 atomic per dim per block
#define CHUNK 256
__global__ __launch_bounds__(128) void gateB(const float* __restrict__ out2, const float* __restrict__ gsc,
                                             const int* __restrict__ kept, const float* __restrict__ b2,
                                             Scal* sc) {
    int d = threadIdx.x;
    float bd = b2[d];
    float gmax = ord2f(sc->gmaxOrd);
    float acc = 0.f, dacc = 0.f, mx = 0.f;
    int start = blockIdx.x * CHUNK;
    int end = start + CHUNK;
    if (end > Nn) end = Nn;
    for (int n = start; n < end; n++) {
        if (!kept[n]) continue;
        float h = fmaxf(out2[(size_t)n * 128 + d] + bd, 0.f);
        float e = expf(gsc[n] - gmax);
        acc += e * h;
        mx = fmaxf(mx, h);
        if (d == 0) dacc += e;
    }
    atomicAdd(&sc->attnum[d], acc);
    atomicMax(&sc->mxOrd[d], f2ord(mx));
    if (d == 0) atomicAdd(&sc->deng, dacc);
}

__global__ void outK(const Scal* sc, float* out) {
    int d = threadIdx.x;
    if (d < 128) {
        out[d] = sc->attnum[d] / sc->deng;
        out[128 + d] = ord2f(sc->mxOrd[d]);
    }
}

extern "C" void kernel_launch(void* const* d_in, const int* in_sizes, int n_in,
                              void* d_out, int out_size, void* d_ws, size_t ws_size,
                              hipStream_t stream) {
    const float* x = (const float*)d_in[0];
    const int* ei = (const int*)d_in[1];
    const float* ea = (const float*)d_in[2];
    const float* W1 = (const float*)d_in[3];
    const float* as1 = (const float*)d_in[4];
    const float* ad1 = (const float*)d_in[5];
    const float* We1 = (const float*)d_in[6];
    const float* ae1 = (const float*)d_in[7];
    const float* b1 = (const float*)d_in[8];
    const float* Wrel = (const float*)d_in[9];
    const float* brel = (const float*)d_in[10];
    const float* Wroot = (const float*)d_in[11];
    const float* W2 = (const float*)d_in[12];
    const float* as2 = (const float*)d_in[13];
    const float* ad2 = (const float*)d_in[14];
    const float* We2 = (const float*)d_in[15];
    const float* ae2 = (const float*)d_in[16];
    const float* b2 = (const float*)d_in[17];
    const float* Wg = (const float*)d_in[18];
    const float* bg = (const float*)d_in[19];
    float* out = (float*)d_out;

    float* base = (float*)d_ws;
    size_t o = 0;
    auto alloc = [&](size_t nf) { float* p = base + o; o += nf; return p; };
    float* hpre = alloc((size_t)Nn * 16);
    float* h1 = alloc((size_t)Nn * 16);
    float* alS1 = alloc((size_t)Nn * 4);
    float* alD1 = alloc((size_t)Nn * 4);
    uint* m1 = (uint*)alloc((size_t)Nn * 4);
    float* den1 = alloc((size_t)Nn * 4);
    float* aggb = alloc((size_t)Nn * 16);
    float* score = alloc(Nn);
    uint* dkey = (uint*)alloc(Nn);
    int* kept = (int*)alloc(Nn);
    float* h2pre = alloc((size_t)Nn * 128);
    float* out2 = alloc((size_t)Nn * 128);
    float* alS2 = alloc(Nn);
    float* alD2 = alloc(Nn);
    uint* m2 = (uint*)alloc(Nn);
    float* den2 = alloc(Nn);
    float* gsc = alloc(Nn);
    uint* hist = (uint*)alloc(256);
    uint* blkLt = (uint*)alloc(NB);
    uint* blkEq = (uint*)alloc(NB);
    uint* eqPref = (uint*)alloc(NB);
    Scal* sc = (Scal*)alloc(512);

    auto cdiv = [](long a, long b) { return (int)((a + b - 1) / b); };

    initK<<<cdiv((long)Nn * 128, 256), 256, 0, stream>>>(h1, m1, den1, aggb, out2, m2, den2, hist, sc);
    constK<<<1, 64, 0, stream>>>(We1, ae1, We2, ae2, sc);
    nodeL1<<<NB, 256, 0, stream>>>(x, W1, as1, ad1, hpre, alS1, alD1);
    edgeMax1<<<cdiv((long)Ee * 4, 256), 256, 0, stream>>>(ei, ea, alS1, alD1, sc, m1);
    edgeSum1<<<cdiv((long)Ee * 4, 256), 256, 0, stream>>>(ei, ea, alS1, alD1, sc, m1, den1);
    edgeScat1<<<cdiv((long)Ee * 16, 256), 256, 0, stream>>>(ei, ea, alS1, alD1, sc, m1, den1, hpre, h1);
    bias1<<<cdiv((long)Nn * 16, 256), 256, 0, stream>>>(h1, b1);
    aggK<<<cdiv((long)Ee * 16, 256), 256, 0, stream>>>(ei, h1, aggb);
    scoreK<<<NB, 256, 0, stream>>>(aggb, h1, Wrel, brel, Wroot, score, dkey);
    for (int shift = 24; shift >= 0; shift -= 8) {
        histK<<<NB, 256, 0, stream>>>(dkey, sc, hist, shift);
        selK<<<1, 64, 0, stream>>>(sc, hist);
    }
    cntK<<<NB, 256, 0, stream>>>(dkey, sc, blkLt, blkEq);
    prefK<<<1, 64, 0, stream>>>(sc, blkLt, blkEq, eqPref);
    keptK<<<NB, 256, 0, stream>>>(dkey, sc, eqPref, kept);
    nodeL2<<<cdiv(Nn, 4), 256, 0, stream>>>(h1, score, kept, W2, as2, ad2, h2pre, alS2, alD2);
    edgeMax2<<<cdiv(Ee, 256), 256, 0, stream>>>(ei, ea, kept, alS2, alD2, sc, m2);
    edgeSum2<<<cdiv(Ee, 256), 256, 0, stream>>>(ei, ea, kept, alS2, alD2, sc, m2, den2);
    edgeScat2<<<cdiv(Ee, 4), 256, 0, stream>>>(ei, ea, kept, alS2, alD2, sc, m2, den2, h2pre, out2);
    h2finA<<<1024, 256, 0, stream>>>(out2, b2, Wg, bg, kept, gsc, sc);
    gateB<<<cdiv(Nn, CHUNK), 128, 0, stream>>>(out2, gsc, kept, b2, sc);
    outK<<<1, 128, 0, stream>>>(sc, out);
}

// Round 3
// 704.077 us; speedup vs baseline: 4.6851x; 1.7525x over previous
//
#include <hip/hip_runtime.h>
#include <hip/hip_bf16.h>

#define Nn 100000
#define Ee 1600000
#define Kk 80000
#define NB ((Nn + 255) / 256)
#define BIGNEG -1e9f

typedef unsigned int uint;

struct Scal {
    uint prefix, remaining, needEq;
    float c1[4];
    float c2;
    uint gmaxOrd;
    float deng;
    float attnum[128];
    uint mxOrd[128];
};

__device__ __forceinline__ uint f2ord(float f) {
    uint b = __float_as_uint(f);
    return (b & 0x80000000u) ? ~b : (b | 0x80000000u);
}
__device__ __forceinline__ float ord2f(uint u) {
    uint b = (u & 0x80000000u) ? (u ^ 0x80000000u) : ~u;
    return __uint_as_float(b);
}
__device__ __forceinline__ float lrelu(float v) { return v > 0.f ? v : 0.2f * v; }

// ---------------- init ----------------
__global__ __launch_bounds__(256) void initK(uint* deg, uint* hist, Scal* sc) {
    int i = blockIdx.x * 256 + threadIdx.x;
    if (i < Nn) deg[i] = 0u;
    if (i < 256) hist[i] = 0u;
    if (i < 128) { sc->attnum[i] = 0.f; sc->mxOrd[i] = f2ord(0.0f); }
    if (i == 0) {
        sc->prefix = 0u; sc->remaining = Kk; sc->needEq = 0u;
        sc->deng = 0.f; sc->gmaxOrd = f2ord(-1e30f);
    }
}

__global__ void constK(const float* We1, const float* ae1, const float* We2, const float* ae2,
                       Scal* sc) {
    if (threadIdx.x == 0) {
        for (int h = 0; h < 4; h++) {
            float s = 0.f;
            for (int d = 0; d < 4; d++) s += We1[h * 4 + d] * ae1[h * 4 + d];
            sc->c1[h] = s;
        }
        float s2 = 0.f;
        for (int d = 0; d < 128; d++) s2 += We2[d] * ae2[d];
        sc->c2 = s2;
    }
}

// ---------------- layer 1: node GEMM + attn coefficients ----------------
__global__ __launch_bounds__(256) void nodeL1(const float* __restrict__ x,
                                              const float* __restrict__ W1,
                                              const float* __restrict__ as1,
                                              const float* __restrict__ ad1,
                                              float* __restrict__ hpre,
                                              float* __restrict__ alS1,
                                              float* __restrict__ alD1) {
    __shared__ float Ws[128 * 16];
    __shared__ float s_as[16], s_ad[16];
    for (int i = threadIdx.x; i < 2048; i += 256) Ws[i] = W1[i];
    if (threadIdx.x < 16) { s_as[threadIdx.x] = as1[threadIdx.x]; s_ad[threadIdx.x] = ad1[threadIdx.x]; }
    __syncthreads();
    int n = blockIdx.x * 256 + threadIdx.x;
    if (n >= Nn) return;
    float acc[16];
#pragma unroll
    for (int j = 0; j < 16; j++) acc[j] = 0.f;
    const float4* xr = (const float4*)(x + (size_t)n * 128);
    for (int t4 = 0; t4 < 32; t4++) {
        float4 xv = xr[t4];
#pragma unroll
        for (int j = 0; j < 16; j++) {
            acc[j] += xv.x * Ws[(t4 * 4 + 0) * 16 + j];
            acc[j] += xv.y * Ws[(t4 * 4 + 1) * 16 + j];
            acc[j] += xv.z * Ws[(t4 * 4 + 2) * 16 + j];
            acc[j] += xv.w * Ws[(t4 * 4 + 3) * 16 + j];
        }
    }
    float* hp = hpre + (size_t)n * 16;
#pragma unroll
    for (int j = 0; j < 16; j++) hp[j] = acc[j];
#pragma unroll
    for (int h = 0; h < 4; h++) {
        float s = 0.f, d = 0.f;
#pragma unroll
        for (int q = 0; q < 4; q++) {
            s += acc[h * 4 + q] * s_as[h * 4 + q];
            d += acc[h * 4 + q] * s_ad[h * 4 + q];
        }
        alS1[n * 4 + h] = s;
        alD1[n * 4 + h] = d;
    }
}

// ---------------- CSR build (dst-sorted) ----------------
__global__ __launch_bounds__(256) void degK(const int* __restrict__ ei, uint* __restrict__ deg) {
    int e = blockIdx.x * 256 + threadIdx.x;
    if (e >= Ee) return;
    atomicAdd(&deg[ei[Ee + e]], 1u);
}

__global__ __launch_bounds__(256) void scanA(const uint* __restrict__ deg, uint* __restrict__ rowstart,
                                             uint* __restrict__ blkSum) {
    __shared__ uint s[256];
    int i = blockIdx.x * 256 + threadIdx.x;
    uint v = (i < Nn) ? deg[i] : 0u;
    s[threadIdx.x] = v;
    __syncthreads();
    for (int off = 1; off < 256; off <<= 1) {
        uint t = (threadIdx.x >= off) ? s[threadIdx.x - off] : 0u;
        __syncthreads();
        s[threadIdx.x] += t;
        __syncthreads();
    }
    if (i < Nn) rowstart[i] = s[threadIdx.x] - v;  // exclusive within block
    if (threadIdx.x == 255) blkSum[blockIdx.x] = s[255];
}

__global__ __launch_bounds__(512) void scanB(const uint* __restrict__ blkSum, uint* __restrict__ blkOff) {
    __shared__ uint s[512];
    uint v = (threadIdx.x < NB) ? blkSum[threadIdx.x] : 0u;
    s[threadIdx.x] = v;
    __syncthreads();
    for (int off = 1; off < 512; off <<= 1) {
        uint t = (threadIdx.x >= off) ? s[threadIdx.x - off] : 0u;
        __syncthreads();
        s[threadIdx.x] += t;
        __syncthreads();
    }
    if (threadIdx.x < NB) blkOff[threadIdx.x] = s[threadIdx.x] - v;
}

__global__ __launch_bounds__(256) void scanC(uint* __restrict__ rowstart, const uint* __restrict__ blkOff,
                                             uint* __restrict__ cursor) {
    int i = blockIdx.x * 256 + threadIdx.x;
    if (i < Nn) {
        rowstart[i] += blkOff[blockIdx.x];
        cursor[i] = 0u;
    }
    if (i == 0) rowstart[Nn] = Ee;
}

__global__ __launch_bounds__(256) void fillK(const int* __restrict__ ei, const float* __restrict__ ea,
                                             const uint* __restrict__ rowstart, uint* __restrict__ cursor,
                                             int* __restrict__ csr_src, float* __restrict__ csr_ea) {
    int e = blockIdx.x * 256 + threadIdx.x;
    if (e >= Ee) return;
    int s = ei[e], d = ei[Ee + e];
    uint pos = atomicAdd(&cursor[d], 1u);
    uint idx = rowstart[d] + pos;
    csr_src[idx] = s;
    csr_ea[idx] = ea[e];
}

// ---------------- layer-1 gather: online softmax, thread per (dst,head) ----------------
__global__ __launch_bounds__(256) void gather1(const int* __restrict__ csr_src, const float* __restrict__ csr_ea,
                                               const uint* __restrict__ rowstart,
                                               const float* __restrict__ hpre, const float* __restrict__ alS1,
                                               const float* __restrict__ alD1, const Scal* __restrict__ sc,
                                               const float* __restrict__ b1, const float* __restrict__ Wrel,
                                               const float* __restrict__ Wroot,
                                               float* __restrict__ h1, float* __restrict__ p,
                                               float* __restrict__ q) {
    int tid = blockIdx.x * 256 + threadIdx.x;
    if (tid >= Nn * 4) return;
    int d = tid >> 2, h = tid & 3;
    uint r0 = rowstart[d], r1 = rowstart[d + 1];
    float ad = alD1[tid];
    float c1h = sc->c1[h];
    float m = -1e30f, den = 0.f;
    float4 acc = {0.f, 0.f, 0.f, 0.f};
    for (uint i = r0; i < r1; i++) {
        int s = csr_src[i];
        float v = lrelu(alS1[s * 4 + h] + ad + csr_ea[i] * c1h);
        float4 hv = *(const float4*)(hpre + (size_t)s * 16 + h * 4);
        if (v > m) {
            float r = __expf(m - v);
            acc.x = acc.x * r + hv.x; acc.y = acc.y * r + hv.y;
            acc.z = acc.z * r + hv.z; acc.w = acc.w * r + hv.w;
            den = den * r + 1.f;
            m = v;
        } else {
            float num = __expf(v - m);
            acc.x += num * hv.x; acc.y += num * hv.y;
            acc.z += num * hv.z; acc.w += num * hv.w;
            den += num;
        }
    }
    float inv = 1.f / fmaxf(den, 1e-16f);
    float4 o;
    o.x = fmaxf(acc.x * inv + b1[h * 4 + 0], 0.f);
    o.y = fmaxf(acc.y * inv + b1[h * 4 + 1], 0.f);
    o.z = fmaxf(acc.z * inv + b1[h * 4 + 2], 0.f);
    o.w = fmaxf(acc.w * inv + b1[h * 4 + 3], 0.f);
    *(float4*)(h1 + (size_t)d * 16 + h * 4) = o;
    // partial dots for GraphConv score: p = h1·Wrel, q = h1·Wroot, reduced over 4 head-lanes
    float pp = o.x * Wrel[h * 4 + 0] + o.y * Wrel[h * 4 + 1] + o.z * Wrel[h * 4 + 2] + o.w * Wrel[h * 4 + 3];
    float qq = o.x * Wroot[h * 4 + 0] + o.y * Wroot[h * 4 + 1] + o.z * Wroot[h * 4 + 2] + o.w * Wroot[h * 4 + 3];
    pp += __shfl_xor(pp, 1); pp += __shfl_xor(pp, 2);
    qq += __shfl_xor(qq, 1); qq += __shfl_xor(qq, 2);
    if (h == 0) { p[d] = pp; q[d] = qq; }
}

// ---------------- SAGPool score: score[d] = brel + q[d] + sum_row p[src] ----------------
__global__ __launch_bounds__(256) void scoreK2(const int* __restrict__ csr_src, const uint* __restrict__ rowstart,
                                               const float* __restrict__ p, const float* __restrict__ q,
                                               const float* __restrict__ brel,
                                               float* __restrict__ score, uint* __restrict__ dkey) {
    int d = blockIdx.x * 256 + threadIdx.x;
    if (d >= Nn) return;
    uint r0 = rowstart[d], r1 = rowstart[d + 1];
    float s = brel[0] + q[d];
    for (uint i = r0; i < r1; i++) s += p[csr_src[i]];
    score[d] = s;
    dkey[d] = ~f2ord(s);  // ascending dkey == descending score
}

// ---------------- radix select (k-th smallest dkey) ----------------
__global__ __launch_bounds__(256) void histK(const uint* __restrict__ dkey, const Scal* __restrict__ sc,
                                             uint* __restrict__ hist, int shift) {
    __shared__ uint lh[256];
    lh[threadIdx.x] = 0u;
    __syncthreads();
    int i = blockIdx.x * 256 + threadIdx.x;
    if (i < Nn) {
        uint d = dkey[i];
        bool ok = (shift == 24) || ((d >> (shift + 8)) == sc->prefix);
        if (ok) atomicAdd(&lh[(d >> shift) & 255u], 1u);
    }
    __syncthreads();
    if (lh[threadIdx.x]) atomicAdd(&hist[threadIdx.x], lh[threadIdx.x]);
}

__global__ void selK(Scal* sc, uint* hist) {
    if (threadIdx.x == 0) {
        uint rem = sc->remaining, cum = 0; int sel = 0;
        for (int b = 0; b < 256; b++) {
            uint c = hist[b];
            if (cum + c >= rem) { sel = b; break; }
            cum += c;
        }
        sc->remaining = rem - cum;
        sc->prefix = (sc->prefix << 8) | (uint)sel;
        for (int b = 0; b < 256; b++) hist[b] = 0u;
    }
}

__global__ __launch_bounds__(256) void cntK(const uint* __restrict__ dkey, const Scal* __restrict__ sc,
                                            uint* __restrict__ blkLt, uint* __restrict__ blkEq) {
    int i = blockIdx.x * 256 + threadIdx.x;
    uint ut = sc->prefix;
    bool lt = (i < Nn) && (dkey[i] < ut);
    bool eq = (i < Nn) && (dkey[i] == ut);
    __shared__ uint sl[4], se[4];
    unsigned long long bl = __ballot(lt), be = __ballot(eq);
    int lane = threadIdx.x & 63, w = threadIdx.x >> 6;
    if (lane == 0) { sl[w] = (uint)__popcll(bl); se[w] = (uint)__popcll(be); }
    __syncthreads();
    if (threadIdx.x == 0) {
        blkLt[blockIdx.x] = sl[0] + sl[1] + sl[2] + sl[3];
        blkEq[blockIdx.x] = se[0] + se[1] + se[2] + se[3];
    }
}

__global__ void prefK(Scal* sc, const uint* blkLt, const uint* blkEq, uint* eqPref) {
    if (threadIdx.x == 0) {
        uint tl = 0, te = 0;
        for (int b = 0; b < NB; b++) {
            eqPref[b] = te;
            tl += blkLt[b];
            te += blkEq[b];
        }
        sc->needEq = Kk - tl;
    }
}

__global__ __launch_bounds__(256) void keptK(const uint* __restrict__ dkey, const Scal* __restrict__ sc,
                                             const uint* __restrict__ eqPref, int* __restrict__ kept) {
    int i = blockIdx.x * 256 + threadIdx.x;
    uint ut = sc->prefix, needEq = sc->needEq;
    bool inr = i < Nn;
    uint d = inr ? dkey[i] : 0xFFFFFFFFu;
    bool isLt = inr && (d < ut);
    bool isEq = inr && (d == ut);
    __shared__ uint wcnt[4];
    unsigned long long mask = __ballot(isEq);
    int lane = threadIdx.x & 63, w = threadIdx.x >> 6;
    uint lanePre = (uint)__popcll(mask & ((1ull << lane) - 1ull));
    if (lane == 0) wcnt[w] = (uint)__popcll(mask);
    __syncthreads();
    uint wo = 0;
    for (int q = 0; q < 4; q++) if (q < w) wo += wcnt[q];
    uint rank = eqPref[blockIdx.x] + wo + lanePre;
    if (inr) kept[i] = (isLt || (isEq && rank < needEq)) ? 1 : 0;
}

// ---------------- layer 2 node transform ----------------
__global__ __launch_bounds__(256) void nodeL2(const float* __restrict__ h1, const float* __restrict__ score,
                                              const int* __restrict__ kept, const float* __restrict__ W2,
                                              const float* __restrict__ as2, const float* __restrict__ ad2,
                                              float* __restrict__ h2pre, float* __restrict__ alS2,
                                              float* __restrict__ alD2) {
    __shared__ float Ws[16 * 128];
    for (int i = threadIdx.x; i < 2048; i += 256) Ws[i] = W2[i];
    __syncthreads();
    int wid = (blockIdx.x * 256 + threadIdx.x) >> 6;
    int lane = threadIdx.x & 63;
    if (wid >= Nn) return;
    int n = wid;
    if (!kept[n]) return;
    float t = tanhf(score[n]);
    float x2[16];
    const float* hr = h1 + (size_t)n * 16;
#pragma unroll
    for (int j = 0; j < 16; j++) x2[j] = hr[j] * t;
    int d0 = lane, d1 = lane + 64;
    float a0 = 0.f, a1 = 0.f;
#pragma unroll
    for (int j = 0; j < 16; j++) {
        a0 += x2[j] * Ws[j * 128 + d0];
        a1 += x2[j] * Ws[j * 128 + d1];
    }
    h2pre[(size_t)n * 128 + d0] = a0;
    h2pre[(size_t)n * 128 + d1] = a1;
    float s = a0 * as2[d0] + a1 * as2[d1];
    float dd = a0 * ad2[d0] + a1 * ad2[d1];
#pragma unroll
    for (int off = 32; off; off >>= 1) { s += __shfl_xor(s, off); dd += __shfl_xor(dd, off); }
    if (lane == 0) { alS2[n] = s; alD2[n] = dd; }
}

// ---------------- layer-2 gather: wave per kept dst, online softmax, fused b2+relu+gate ----------------
__global__ __launch_bounds__(256) void gather2(const int* __restrict__ csr_src, const float* __restrict__ csr_ea,
                                               const uint* __restrict__ rowstart, const int* __restrict__ kept,
                                               const float* __restrict__ alS2, const float* __restrict__ alD2,
                                               const Scal* __restrict__ scc,
                                               const float* __restrict__ h2pre, const float* __restrict__ b2,
                                               const float* __restrict__ Wg, const float* __restrict__ bg,
                                               float* __restrict__ out2, float* __restrict__ gsc,
                                               Scal* sc) {
    __shared__ float wmax[4];
    int w = threadIdx.x >> 6, lane = threadIdx.x & 63;
    float b2a = b2[lane], b2b = b2[lane + 64];
    float wga = Wg[lane], wgb = Wg[lane + 64];
    float c2 = scc->c2;
    float bg0 = bg[0];
    float lmax = -1e30f;
    for (int n = blockIdx.x * 4 + w; n < Nn; n += gridDim.x * 4) {
        if (!kept[n]) continue;
        float ad = alD2[n];
        uint r0 = rowstart[n], r1 = rowstart[n + 1];
        float m = -1e30f, den = 0.f, a0 = 0.f, a1 = 0.f;
        for (uint i = r0; i < r1; i++) {
            int s = csr_src[i];
            if (!kept[s]) continue;
            float v = lrelu(alS2[s] + ad + csr_ea[i] * c2);
            float h0 = h2pre[(size_t)s * 128 + lane];
            float h1v = h2pre[(size_t)s * 128 + lane + 64];
            if (v > m) {  // wave-uniform branch
                float r = __expf(m - v);
                a0 = a0 * r + h0; a1 = a1 * r + h1v;
                den = den * r + 1.f;
                m = v;
            } else {
                float num = __expf(v - m);
                a0 += num * h0; a1 += num * h1v;
                den += num;
            }
        }
        float inv = 1.f / fmaxf(den, 1e-16f);
        float o0 = fmaxf(a0 * inv + b2a, 0.f);
        float o1 = fmaxf(a1 * inv + b2b, 0.f);
        out2[(size_t)n * 128 + lane] = o0;
        out2[(size_t)n * 128 + lane + 64] = o1;
        float g = o0 * wga + o1 * wgb;
#pragma unroll
        for (int off = 32; off; off >>= 1) g += __shfl_xor(g, off);
        g += bg0;
        if (lane == 0) gsc[n] = g;
        lmax = fmaxf(lmax, g);
    }
    if (lane == 0) wmax[w] = lmax;
    __syncthreads();
    if (threadIdx.x == 0) {
        float m = fmaxf(fmaxf(wmax[0], wmax[1]), fmaxf(wmax[2], wmax[3]));
        atomicMax(&sc->gmaxOrd, f2ord(m));
    }
}

// gate-weighted sum + per-dim column max; out2 is already post-bias+relu
#define CHUNK 256
__global__ __launch_bounds__(128) void gateB(const float* __restrict__ out2, const float* __restrict__ gsc,
                                             const int* __restrict__ kept, Scal* sc) {
    int d = threadIdx.x;
    float gmax = ord2f(sc->gmaxOrd);
    float acc = 0.f, dacc = 0.f, mx = 0.f;
    int start = blockIdx.x * CHUNK;
    int end = start + CHUNK;
    if (end > Nn) end = Nn;
    for (int n = start; n < end; n++) {
        if (!kept[n]) continue;
        float h = out2[(size_t)n * 128 + d];
        float e = __expf(gsc[n] - gmax);
        acc += e * h;
        mx = fmaxf(mx, h);
        if (d == 0) dacc += e;
    }
    atomicAdd(&sc->attnum[d], acc);
    atomicMax(&sc->mxOrd[d], f2ord(mx));
    if (d == 0) atomicAdd(&sc->deng, dacc);
}

__global__ void outK(const Scal* sc, float* out) {
    int d = threadIdx.x;
    if (d < 128) {
        out[d] = sc->attnum[d] / sc->deng;
        out[128 + d] = ord2f(sc->mxOrd[d]);
    }
}

extern "C" void kernel_launch(void* const* d_in, const int* in_sizes, int n_in,
                              void* d_out, int out_size, void* d_ws, size_t ws_size,
                              hipStream_t stream) {
    const float* x = (const float*)d_in[0];
    const int* ei = (const int*)d_in[1];
    const float* ea = (const float*)d_in[2];
    const float* W1 = (const float*)d_in[3];
    const float* as1 = (const float*)d_in[4];
    const float* ad1 = (const float*)d_in[5];
    const float* We1 = (const float*)d_in[6];
    const float* ae1 = (const float*)d_in[7];
    const float* b1 = (const float*)d_in[8];
    const float* Wrel = (const float*)d_in[9];
    const float* brel = (const float*)d_in[10];
    const float* Wroot = (const float*)d_in[11];
    const float* W2 = (const float*)d_in[12];
    const float* as2 = (const float*)d_in[13];
    const float* ad2 = (const float*)d_in[14];
    const float* We2 = (const float*)d_in[15];
    const float* ae2 = (const float*)d_in[16];
    const float* b2 = (const float*)d_in[17];
    const float* Wg = (const float*)d_in[18];
    const float* bg = (const float*)d_in[19];
    float* out = (float*)d_out;

    float* base = (float*)d_ws;
    // Union region U (12.8M floats): out2 aliases all early-dead buffers.
    // Everything in U is dead before gather2 writes out2.
    float* out2 = base;                               // [12.8M] written by gather2
    size_t o = 0;
    auto allocU = [&](size_t nf) { float* p2 = base + o; o += nf; return p2; };
    float* hpre = allocU((size_t)Nn * 16);            // dead after gather1
    float* h1 = allocU((size_t)Nn * 16);              // dead after nodeL2
    float* alS1 = allocU((size_t)Nn * 4);             // dead after gather1
    float* alD1 = allocU((size_t)Nn * 4);             // dead after gather1
    float* p = allocU(Nn);                            // dead after scoreK2
    float* q = allocU(Nn);                            // dead after scoreK2
    float* score = allocU(Nn);                        // dead after nodeL2
    uint* dkey = (uint*)allocU(Nn);                   // dead after keptK
    uint* deg = (uint*)allocU(Nn);                    // dead after scanA; reused as cursor
    uint* blkSum = (uint*)allocU(NB);
    uint* blkOff = (uint*)allocU(NB);
    uint* hist = (uint*)allocU(256);
    uint* blkLt = (uint*)allocU(NB);
    uint* blkEq = (uint*)allocU(NB);
    uint* eqPref = (uint*)allocU(NB);
    // o is ~4.5M < 12.8M — U fits under out2.
    size_t oo = (size_t)Nn * 128;                     // start of persistent region
    auto alloc = [&](size_t nf) { float* p2 = base + oo; oo += nf; return p2; };
    float* h2pre = alloc((size_t)Nn * 128);
    int* csr_src = (int*)alloc(Ee);
    float* csr_ea = alloc(Ee);
    uint* rowstart = (uint*)alloc(Nn + 1);
    int* kept = (int*)alloc(Nn);
    float* alS2 = alloc(Nn);
    float* alD2 = alloc(Nn);
    float* gsc = alloc(Nn);
    Scal* sc = (Scal*)alloc(512);
    uint* cursor = deg;  // alias: deg dead after scanA, cursor zeroed in scanC

    auto cdiv = [](long a, long b) { return (int)((a + b - 1) / b); };

    initK<<<NB, 256, 0, stream>>>(deg, hist, sc);
    constK<<<1, 64, 0, stream>>>(We1, ae1, We2, ae2, sc);
    nodeL1<<<NB, 256, 0, stream>>>(x, W1, as1, ad1, hpre, alS1, alD1);
    degK<<<cdiv(Ee, 256), 256, 0, stream>>>(ei, deg);
    scanA<<<NB, 256, 0, stream>>>(deg, rowstart, blkSum);
    scanB<<<1, 512, 0, stream>>>(blkSum, blkOff);
    scanC<<<NB, 256, 0, stream>>>(rowstart, blkOff, cursor);
    fillK<<<cdiv(Ee, 256), 256, 0, stream>>>(ei, ea, rowstart, cursor, csr_src, csr_ea);
    gather1<<<cdiv((long)Nn * 4, 256), 256, 0, stream>>>(csr_src, csr_ea, rowstart, hpre, alS1, alD1,
                                                         sc, b1, Wrel, Wroot, h1, p, q);
    scoreK2<<<NB, 256, 0, stream>>>(csr_src, rowstart, p, q, brel, score, dkey);
    for (int shift = 24; shift >= 0; shift -= 8) {
        histK<<<NB, 256, 0, stream>>>(dkey, sc, hist, shift);
        selK<<<1, 64, 0, stream>>>(sc, hist);
    }
    cntK<<<NB, 256, 0, stream>>>(dkey, sc, blkLt, blkEq);
    prefK<<<1, 64, 0, stream>>>(sc, blkLt, blkEq, eqPref);
    keptK<<<NB, 256, 0, stream>>>(dkey, sc, eqPref, kept);
    nodeL2<<<cdiv(Nn, 4), 256, 0, stream>>>(h1, score, kept, W2, as2, ad2, h2pre, alS2, alD2);
    gather2<<<2048, 256, 0, stream>>>(csr_src, csr_ea, rowstart, kept, alS2, alD2, sc,
                                      h2pre, b2, Wg, bg, out2, gsc, sc);
    gateB<<<cdiv(Nn, CHUNK), 128, 0, stream>>>(out2, gsc, kept, sc);
    outK<<<1, 128, 0, stream>>>(sc, out);
}